// Round 4
// baseline (649.657 us; speedup 1.0000x reference)
//
#include <hip/hip_runtime.h>
#include <stdint.h>

// MS-SSIM + L1 fused loss, MI355X.
// R3 change (single variable): pin occupancy with amdgpu_waves_per_eu(2,2)
// so the register allocator plans 2 waves/EU -> up to 256 VGPR, instead of
// its 128-VGPR/4-wave heuristic that spilled 400-900MB/launch to scratch
// (R0-R2 all show VGPR_Count=128 + huge WRITE_SIZE in a kernel that
// architecturally writes 4KB). Weights back to runtime expf + readfirstlane
// (R1 best form); constexpr-literal weights regressed in R2.

#define TILE 64
#define HALO 16
#define HA   96      // halo extent (TILE + 2*HALO)
#define XSTR 96      // ushort stride of Xs/Ys rows
#define HSTR 68      // float stride of H-plane rows
#define NTHREADS 512

#define C1c 1.0e-4f  // (0.01*DR)^2
#define C2c 9.0e-4f  // (0.03*DR)^2

__device__ __forceinline__ float bf2f(unsigned short h) {
  union { unsigned int u; float f; } c; c.u = ((unsigned int)h) << 16; return c.f;
}
__device__ __forceinline__ unsigned short f2bf(float f) {
  union { float f; unsigned int u; } c; c.f = f;
  unsigned int r = (c.u + 0x7FFFu + ((c.u >> 16) & 1u)) >> 16;
  return (unsigned short)r;
}
__device__ __forceinline__ float uniform_f(float x) {
  union { float f; int i; } c; c.f = x;
  c.i = __builtin_amdgcn_readfirstlane(c.i);
  return c.f;
}

__device__ __forceinline__ void unpack8(uint4 u, float* v) {
  union { unsigned int u32; float f; } c;
  c.u32 = u.x << 16;         v[0] = c.f;
  c.u32 = u.x & 0xFFFF0000u; v[1] = c.f;
  c.u32 = u.y << 16;         v[2] = c.f;
  c.u32 = u.y & 0xFFFF0000u; v[3] = c.f;
  c.u32 = u.z << 16;         v[4] = c.f;
  c.u32 = u.z & 0xFFFF0000u; v[5] = c.f;
  c.u32 = u.w << 16;         v[6] = c.f;
  c.u32 = u.w & 0xFFFF0000u; v[7] = c.f;
}

// Horizontal pass, streaming form. Q: 0=x, 1=y, 2=x*x, 3=y*y, 4=x*y, 5=|x-y|
template<int R, int Q>
__device__ __forceinline__ void hpass(const unsigned short* __restrict__ Xs,
                                      const unsigned short* __restrict__ Ys,
                                      float* __restrict__ Hs,
                                      const float* __restrict__ w, int tid) {
  constexpr int START = HALO - R;          // leftmost rel. input col for colgroup 0
  constexpr int ABASE = START & ~7;        // align to 8 bf16 (16B)
  constexpr int OFF   = START - ABASE;
  constexpr int WIN   = 2 * R + 8;         // window floats per 8 outputs
  constexpr int NV    = (OFF + WIN + 7) >> 3;
  constexpr int ROWS  = TILE + 2 * R;      // rows the V-pass will consume
  constexpr int NS    = 8 * ROWS;          // strips (8 colgroups x ROWS)
  static_assert(OFF + 7 + 2 * R <= NV * 8 - 1, "window fits");
  for (int s = tid; s < NS; s += NTHREADS) {
    const int g = s & 7;
    const int r = (s >> 3) + (HALO - R);
    const int base = r * XSTR + ABASE + g * 8;
    const uint4* qx = (const uint4*)(Xs + base);
    const uint4* qy = (const uint4*)(Ys + base);
    float acc[8] = {0.f,0.f,0.f,0.f,0.f,0.f,0.f,0.f};
    #pragma unroll
    for (int j = 0; j < NV; ++j) {
      float val[8];
      if (Q == 0) {
        unpack8(qx[j], val);
      } else if (Q == 1) {
        unpack8(qy[j], val);
      } else if (Q == 2) {
        unpack8(qx[j], val);
        #pragma unroll
        for (int jj = 0; jj < 8; ++jj) val[jj] *= val[jj];
      } else if (Q == 3) {
        unpack8(qy[j], val);
        #pragma unroll
        for (int jj = 0; jj < 8; ++jj) val[jj] *= val[jj];
      } else {
        float vy[8];
        unpack8(qx[j], val);
        unpack8(qy[j], vy);
        if (Q == 4) {
          #pragma unroll
          for (int jj = 0; jj < 8; ++jj) val[jj] *= vy[jj];
        } else {
          #pragma unroll
          for (int jj = 0; jj < 8; ++jj) val[jj] = fabsf(val[jj] - vy[jj]);
        }
      }
      #pragma unroll
      for (int jj = 0; jj < 8; ++jj) {
        const int k = j * 8 + jj;        // window index (compile-time)
        #pragma unroll
        for (int o = 0; o < 8; ++o) {
          const int wi = k - OFF - o;    // tap index (compile-time)
          if (wi >= 0 && wi <= 2 * R)
            acc[o] = fmaf(w[wi], val[jj], acc[o]);
        }
      }
    }
    float4* dst = (float4*)(Hs + r * HSTR + g * 8);
    dst[0] = make_float4(acc[0], acc[1], acc[2], acc[3]);
    dst[1] = make_float4(acc[4], acc[5], acc[6], acc[7]);
  }
}

template<int R>
__device__ __forceinline__ void vpass(const float* __restrict__ Hs,
                                      const float* __restrict__ w,
                                      int tid, float* __restrict__ out) {
  const int c  = tid & 63;
  const int rg = tid >> 6;
  const int rbase = rg * 8 + HALO - R;
  float acc[8] = {0.f,0.f,0.f,0.f,0.f,0.f,0.f,0.f};
  #pragma unroll
  for (int i = 0; i < 2 * R + 8; ++i) {
    float hv = Hs[(rbase + i) * HSTR + c];
    #pragma unroll
    for (int o = 0; o < 8; ++o) {
      if (i - o >= 0 && i - o <= 2 * R)
        acc[o] = fmaf(w[i - o], hv, acc[o]);
    }
  }
  #pragma unroll
  for (int o = 0; o < 8; ++o) out[o] = acc[o];
}

template<int R>
__device__ __forceinline__ void mkweights(float sigma, float* w) {
  const float inv = 1.0f / (2.0f * sigma * sigma);
  float s = 0.0f;
  for (int k = -16; k <= 16; ++k) s += expf(-(float)(k * k) * inv);
  const float si = 1.0f / s;
  #pragma unroll
  for (int k = 0; k <= 2 * R; ++k) {
    const int d = k - R;
    w[k] = uniform_f(expf(-(float)(d * d) * inv) * si);
  }
}

// One full (sigma) SSIM pass; keeps only A=mux*muy, B=mux^2+muy^2 across
// sub-passes; folds l^3 into PIcs when LAST.
template<int R, int MULT, bool LAST>
__device__ __forceinline__ void do_sigma(float sigma,
                                         const unsigned short* Xs,
                                         const unsigned short* Ys,
                                         float* Hs, int tid, float* PIcs) {
  float w[2 * R + 1];
  mkweights<R>(sigma, w);
  float A[8], B[8], S[8], t[8];
  // mux
  hpass<R,0>(Xs, Ys, Hs, w, tid); __syncthreads(); vpass<R>(Hs, w, tid, A); __syncthreads();
  // muy
  hpass<R,1>(Xs, Ys, Hs, w, tid); __syncthreads(); vpass<R>(Hs, w, tid, t); __syncthreads();
  #pragma unroll
  for (int i = 0; i < 8; ++i) {
    const float mux = A[i], muy = t[i];
    A[i] = mux * muy;
    B[i] = mux * mux + muy * muy;
  }
  // E[x^2]
  hpass<R,2>(Xs, Ys, Hs, w, tid); __syncthreads(); vpass<R>(Hs, w, tid, S); __syncthreads();
  // E[y^2] -> S = sx2 + sy2
  hpass<R,3>(Xs, Ys, Hs, w, tid); __syncthreads(); vpass<R>(Hs, w, tid, t); __syncthreads();
  #pragma unroll
  for (int i = 0; i < 8; ++i) S[i] = S[i] + t[i] - B[i];
  // E[xy] -> cs
  hpass<R,4>(Xs, Ys, Hs, w, tid); __syncthreads(); vpass<R>(Hs, w, tid, t); __syncthreads();
  #pragma unroll
  for (int i = 0; i < 8; ++i) {
    const float sxy = t[i] - A[i];
    const float cs = (2.f * sxy + C2c) / (S[i] + C2c);
    float p = cs;
    if (MULT >= 2) p *= cs;
    if (MULT >= 3) p *= cs;
    if (LAST) {
      const float l = (2.f * A[i] + C1c) / (B[i] + C1c);
      p *= l * l * l;
    }
    PIcs[i] *= p;
  }
}

template<int R>
__device__ __forceinline__ void do_l1(float sigma,
                                      const unsigned short* Xs,
                                      const unsigned short* Ys,
                                      float* Hs, int tid, float* gl1) {
  float w[2 * R + 1];
  mkweights<R>(sigma, w);
  float rr[8];
  hpass<R,5>(Xs, Ys, Hs, w, tid); __syncthreads(); vpass<R>(Hs, w, tid, rr); __syncthreads();
  #pragma unroll
  for (int i = 0; i < 8; ++i) gl1[i] += rr[i];
}

__global__ __launch_bounds__(NTHREADS)
__attribute__((amdgpu_waves_per_eu(2, 2)))
void msssim_fused_kernel(const float* __restrict__ x, const float* __restrict__ y,
                         float* __restrict__ partials) {
  __shared__ unsigned short Xs[HA * XSTR];
  __shared__ unsigned short Ys[HA * XSTR];
  __shared__ float Hs[HA * HSTR];
  __shared__ float red[16];

  const int tid = threadIdx.x;
  const int bx = blockIdx.x, by = blockIdx.y, b = blockIdx.z;
  const int y0 = by * TILE - HALO;
  const int x0 = bx * TILE - HALO;

  float PIcs[8], gl1[8];
  #pragma unroll
  for (int i = 0; i < 8; ++i) { PIcs[i] = 1.f; gl1[i] = 0.f; }
  float absacc = 0.f;

  for (int ch = 0; ch < 3; ++ch) {
    __syncthreads();   // protect Xs/Ys from prior channel readers
    const float* __restrict__ xs = x + (size_t)(b * 3 + ch) * 512 * 512;
    const float* __restrict__ ys = y + (size_t)(b * 3 + ch) * 512 * 512;
    for (int idx = tid; idx < HA * HA; idx += NTHREADS) {
      const int r  = idx / HA;
      const int cc = idx - r * HA;
      const int gy = y0 + r, gx = x0 + cc;
      const bool ok = (gy >= 0) && (gy < 512) && (gx >= 0) && (gx < 512);
      float xv = 0.f, yv = 0.f;
      if (ok) { xv = xs[gy * 512 + gx] * 0.5f + 0.5f; yv = ys[gy * 512 + gx] * 0.5f + 0.5f; }
      Xs[idx] = ok ? f2bf(xv) : (unsigned short)0;
      Ys[idx] = ok ? f2bf(yv) : (unsigned short)0;
    }
    __syncthreads();

    { // plain per-pixel |x-y| for gen-loss L1 (denormalized x,y)
      const int c = tid & 63, rg = tid >> 6;
      #pragma unroll
      for (int i = 0; i < 8; ++i) {
        const int hidx = (HALO + rg * 8 + i) * XSTR + HALO + c;
        absacc += fabsf(bf2f(Xs[hidx]) - bf2f(Ys[hidx]));
      }
    }

    if (ch == 0) {
      do_sigma<4, 3, false>(0.5f, Xs, Ys, Hs, tid, PIcs);
      do_sigma<7, 2, false>(1.0f, Xs, Ys, Hs, tid, PIcs);
      do_l1<16>(8.0f, Xs, Ys, Hs, tid, gl1);
    } else if (ch == 1) {
      do_sigma<7, 1, false>(1.0f, Xs, Ys, Hs, tid, PIcs);
      do_sigma<13, 3, false>(2.0f, Xs, Ys, Hs, tid, PIcs);
      do_sigma<16, 1, false>(4.0f, Xs, Ys, Hs, tid, PIcs);
      do_l1<16>(8.0f, Xs, Ys, Hs, tid, gl1);
    } else {
      do_sigma<16, 2, false>(4.0f, Xs, Ys, Hs, tid, PIcs);
      do_sigma<16, 3, true>(8.0f, Xs, Ys, Hs, tid, PIcs);
      do_l1<16>(8.0f, Xs, Ys, Hs, tid, gl1);
    }
  }

  float mixsum = 0.f;
  #pragma unroll
  for (int i = 0; i < 8; ++i) {
    const float ssim = 1.f - PIcs[i];
    mixsum += 200.f * (0.025f * ssim + 0.975f * (gl1[i] * (1.f / 3.f)));
  }

  // block reduction of mixsum and absacc
  #pragma unroll
  for (int off = 32; off > 0; off >>= 1) {
    mixsum += __shfl_down(mixsum, off);
    absacc += __shfl_down(absacc, off);
  }
  const int wave = tid >> 6, lane = tid & 63;
  if (lane == 0) { red[wave] = mixsum; red[8 + wave] = absacc; }
  __syncthreads();
  if (tid == 0) {
    float m = 0.f, a = 0.f;
    #pragma unroll
    for (int i = 0; i < 8; ++i) { m += red[i]; a += red[8 + i]; }
    const int blk = (b * 8 + by) * 8 + bx;
    partials[2 * blk + 0] = m;
    partials[2 * blk + 1] = a;
  }
}

__global__ __launch_bounds__(512)
void msssim_final_kernel(const float* __restrict__ partials,
                         const float* __restrict__ disc,
                         float* __restrict__ out) {
  __shared__ float red[24];
  const int tid = threadIdx.x;
  float m = 0.f, a = 0.f, d2 = 0.f;
  { // exactly one partial pair per thread (512 blocks, 512 threads)
    m = partials[2 * tid + 0];
    a = partials[2 * tid + 1];
  }
  for (int i = tid; i < 8 * 62 * 62; i += 512) {
    const float d = disc[i] - 1.f;
    d2 = fmaf(d, d, d2);
  }
  #pragma unroll
  for (int off = 32; off > 0; off >>= 1) {
    m  += __shfl_down(m, off);
    a  += __shfl_down(a, off);
    d2 += __shfl_down(d2, off);
  }
  const int wave = tid >> 6, lane = tid & 63;
  if (lane == 0) { red[wave] = m; red[8 + wave] = a; red[16 + wave] = d2; }
  __syncthreads();
  if (tid == 0) {
    float sm = 0.f, sa = 0.f, sd = 0.f;
    #pragma unroll
    for (int i = 0; i < 8; ++i) { sm += red[i]; sa += red[8 + i]; sd += red[16 + i]; }
    const float mix_mean  = sm / (8.f * 512.f * 512.f);
    const float abs_mean  = sa / (8.f * 3.f * 512.f * 512.f);
    const float disc_mean = sd / (8.f * 62.f * 62.f);
    out[0] = 0.5f * (mix_mean + 100.f * abs_mean + disc_mean);
  }
}

extern "C" void kernel_launch(void* const* d_in, const int* in_sizes, int n_in,
                              void* d_out, int out_size, void* d_ws, size_t ws_size,
                              hipStream_t stream) {
  const float* x    = (const float*)d_in[0];
  const float* y    = (const float*)d_in[1];
  const float* disc = (const float*)d_in[2];
  // d_in[3] = g_masks (unused: weights are recomputed exactly on device)
  float* partials = (float*)d_ws;   // 512 * 2 floats, fully overwritten each call
  dim3 grid(8, 8, 8);
  msssim_fused_kernel<<<grid, NTHREADS, 0, stream>>>(x, y, partials);
  msssim_final_kernel<<<1, 512, 0, stream>>>(partials, disc, (float*)d_out);
}

// Round 5
// 567.317 us; speedup vs baseline: 1.1451x; 1.1451x over previous
//
#include <hip/hip_runtime.h>
#include <stdint.h>

// MS-SSIM + L1 fused loss, MI355X.
// R4: structural register-pressure fix. R1-R3 all spilled (WRITE_SIZE
// 0.44-1.35 GB in a kernel that writes 4KB; VGPR pinned 128 by allocator
// heuristic regardless of launch_bounds/waves_per_eu). This version shrinks
// the true working set so 128 VGPRs suffice:
//  - TILE 32, 256 threads, 4 px/thread (half of every per-thread array)
//  - fused 5-quantity H/V passes (x,y,x2,y2,xy in ONE window sweep,
//    acc[5][4]=20 regs) -> 5 LDS planes -> one fused V-pass
//  - x/y interleaved bf16 in LDS: one ds_read_b128 = 4 (x,y) pairs
//  - distance-indexed weights wt[R+1] (<=17 wave-uniform values)
// LDS: 17.4KB XY + 40KB planes = 58.4KB -> 2 blocks/CU.

#define TILE 32
#define HALO 16
#define WIN  64        // TILE + 2*HALO
#define XYSTR 136      // ushorts per XY row (64 px * 2 interleaved + pad to 16B mult)
#define PSTR 32        // floats per plane row
#define PROWS 64       // plane rows allocated (max TILE+2*R)
#define NT   256

#define C1c 1.0e-4f    // (0.01*DR)^2
#define C2c 9.0e-4f    // (0.03*DR)^2

__device__ __forceinline__ float bf2f_lo(unsigned int u) {
  union { unsigned int u; float f; } c; c.u = u << 16; return c.f;
}
__device__ __forceinline__ float bf2f_hi(unsigned int u) {
  union { unsigned int u; float f; } c; c.u = u & 0xFFFF0000u; return c.f;
}
__device__ __forceinline__ unsigned short f2bf(float f) {
  union { float f; unsigned int u; } c; c.f = f;
  unsigned int r = (c.u + 0x7FFFu + ((c.u >> 16) & 1u)) >> 16;
  return (unsigned short)r;
}
__device__ __forceinline__ float uniform_f(float x) {
  union { float f; int i; } c; c.f = x;
  c.i = __builtin_amdgcn_readfirstlane(c.i);
  return c.f;
}

// wt[j] = normalized gaussian weight at distance j (j=0..R); truncated tails,
// but normalization uses the full 33-tap sum (matches reference kernel).
template<int R>
__device__ __forceinline__ void mkweights(float sigma, float* wt) {
  const float inv = 1.0f / (2.0f * sigma * sigma);
  float s = 0.0f;
  for (int k = -16; k <= 16; ++k) s += expf(-(float)(k * k) * inv);
  const float si = 1.0f / s;
  #pragma unroll
  for (int j = 0; j <= R; ++j)
    wt[j] = uniform_f(expf(-(float)(j * j) * inv) * si);
}

// Fused horizontal pass. NQ=5: {x, y, x2, y2, xy}; NQ=1: {|x-y|}.
// Writes plane q rows pr=0..TILE+2R-1 (input row pr + HALO - R).
template<int R, int NQ>
__device__ __forceinline__ void hpassF(const unsigned short* __restrict__ XY,
                                       float* __restrict__ P,
                                       const float* __restrict__ wt, int tid) {
  constexpr int ROWS  = TILE + 2 * R;
  constexpr int NS    = 8 * ROWS;          // 8 col-groups of 4 px
  constexpr int START = HALO - R;          // input col of tap wi=0 for group 0, out 0
  constexpr int ABASE = START & ~3;        // align to 4 px (16B interleaved)
  constexpr int OFF   = START - ABASE;
  constexpr int NC    = (OFF + 2 * R + 4 + 3) >> 2;   // chunks of 4 px
  for (int s = tid; s < NS; s += NT) {
    const int g  = s & 7;
    const int pr = s >> 3;
    const int ir = pr + (HALO - R);
    const uint4* q4 = (const uint4*)(XY + ir * XYSTR + (g * 4 + ABASE) * 2);
    float acc[NQ][4];
    #pragma unroll
    for (int q = 0; q < NQ; ++q)
      #pragma unroll
      for (int o = 0; o < 4; ++o) acc[q][o] = 0.f;
    #pragma unroll
    for (int c = 0; c < NC; ++c) {
      const uint4 u = q4[c];
      float vx[4], vy[4];
      vx[0] = bf2f_lo(u.x); vy[0] = bf2f_hi(u.x);
      vx[1] = bf2f_lo(u.y); vy[1] = bf2f_hi(u.y);
      vx[2] = bf2f_lo(u.z); vy[2] = bf2f_hi(u.z);
      vx[3] = bf2f_lo(u.w); vy[3] = bf2f_hi(u.w);
      #pragma unroll
      for (int jj = 0; jj < 4; ++jj) {
        const int k = c * 4 + jj;
        float vq[NQ];
        if (NQ == 5) {
          vq[0] = vx[jj]; vq[1] = vy[jj];
          vq[2] = vx[jj] * vx[jj]; vq[3] = vy[jj] * vy[jj];
          vq[4] = vx[jj] * vy[jj];
        } else {
          vq[0] = fabsf(vx[jj] - vy[jj]);
        }
        #pragma unroll
        for (int o = 0; o < 4; ++o) {
          const int wi = k - OFF - o;          // tap offset, compile-time
          if (wi >= 0 && wi <= 2 * R) {
            const int d = (wi > R) ? (wi - R) : (R - wi);
            #pragma unroll
            for (int q = 0; q < NQ; ++q)
              acc[q][o] = fmaf(wt[d], vq[q], acc[q][o]);
          }
        }
      }
    }
    #pragma unroll
    for (int q = 0; q < NQ; ++q) {
      float4* dst = (float4*)(P + q * PROWS * PSTR + pr * PSTR + g * 4);
      *dst = make_float4(acc[q][0], acc[q][1], acc[q][2], acc[q][3]);
    }
  }
}

// Fused vertical pass: thread owns col c=tid&31, out rows rg*4..rg*4+3.
template<int R, int NQ>
__device__ __forceinline__ void vpassF(const float* __restrict__ P,
                                       const float* __restrict__ wt, int tid,
                                       float acc[NQ][4]) {
  const int c  = tid & 31;
  const int rg = tid >> 5;
  #pragma unroll
  for (int q = 0; q < NQ; ++q)
    #pragma unroll
    for (int o = 0; o < 4; ++o) acc[q][o] = 0.f;
  #pragma unroll
  for (int i = 0; i < 2 * R + 4; ++i) {
    const int pr = rg * 4 + i;
    float hv[NQ];
    #pragma unroll
    for (int q = 0; q < NQ; ++q) hv[q] = P[q * PROWS * PSTR + pr * PSTR + c];
    #pragma unroll
    for (int o = 0; o < 4; ++o) {
      const int wi = i - o;
      if (wi >= 0 && wi <= 2 * R) {
        const int d = (wi > R) ? (wi - R) : (R - wi);
        #pragma unroll
        for (int q = 0; q < NQ; ++q)
          acc[q][o] = fmaf(wt[d], hv[q], acc[q][o]);
      }
    }
  }
}

template<int R, int MULT, bool LAST>
__device__ __forceinline__ void ssim_pass(float sigma,
                                          const unsigned short* __restrict__ XY,
                                          float* __restrict__ P, int tid,
                                          float* __restrict__ PIcs) {
  float wt[R + 1];
  mkweights<R>(sigma, wt);
  hpassF<R, 5>(XY, P, wt, tid);
  __syncthreads();
  float acc[5][4];
  vpassF<R, 5>(P, wt, tid, acc);
  __syncthreads();
  #pragma unroll
  for (int o = 0; o < 4; ++o) {
    const float mux = acc[0][o], muy = acc[1][o];
    const float A = mux * muy;
    const float B = mux * mux + muy * muy;
    const float S = acc[2][o] + acc[3][o] - B;
    const float sxy = acc[4][o] - A;
    const float cs = (2.f * sxy + C2c) / (S + C2c);
    float p = cs;
    if (MULT >= 2) p *= cs;
    if (MULT >= 3) p *= cs;
    if (LAST) {
      const float l = (2.f * A + C1c) / (B + C1c);
      p *= l * l * l;
    }
    PIcs[o] *= p;
  }
}

template<int R>
__device__ __forceinline__ void l1_pass(float sigma,
                                        const unsigned short* __restrict__ XY,
                                        float* __restrict__ P, int tid,
                                        float* __restrict__ gl1) {
  float wt[R + 1];
  mkweights<R>(sigma, wt);
  hpassF<R, 1>(XY, P, wt, tid);
  __syncthreads();
  float acc[1][4];
  vpassF<R, 1>(P, wt, tid, acc);
  __syncthreads();
  #pragma unroll
  for (int o = 0; o < 4; ++o) gl1[o] += acc[0][o];
}

__global__ __launch_bounds__(NT)
void msssim_fused_kernel(const float* __restrict__ x, const float* __restrict__ y,
                         float* __restrict__ partials) {
  __shared__ unsigned short XY[WIN * XYSTR];    // interleaved (x,y) bf16
  __shared__ float P[5 * PROWS * PSTR];         // H-planes
  __shared__ float red[8];

  const int tid = threadIdx.x;
  const int bx = blockIdx.x, by = blockIdx.y, b = blockIdx.z;
  const int x0 = bx * TILE - HALO;
  const int y0 = by * TILE - HALO;

  float PIcs[4] = {1.f, 1.f, 1.f, 1.f};
  float gl1[4]  = {0.f, 0.f, 0.f, 0.f};
  float absacc  = 0.f;

  for (int ch = 0; ch < 3; ++ch) {
    __syncthreads();   // XY may still have readers from previous channel
    const float* __restrict__ xs = x + (size_t)(b * 3 + ch) * 512 * 512;
    const float* __restrict__ ys = y + (size_t)(b * 3 + ch) * 512 * 512;
    for (int idx = tid; idx < WIN * WIN; idx += NT) {
      const int r  = idx >> 6;
      const int cc = idx & 63;
      const int gy = y0 + r, gx = x0 + cc;
      const bool ok = (gy >= 0) && (gy < 512) && (gx >= 0) && (gx < 512);
      float xv = 0.f, yv = 0.f;
      if (ok) { xv = xs[gy * 512 + gx] * 0.5f + 0.5f; yv = ys[gy * 512 + gx] * 0.5f + 0.5f; }
      const unsigned int packed = (unsigned int)f2bf(xv) | ((unsigned int)f2bf(yv) << 16);
      *(unsigned int*)(XY + r * XYSTR + cc * 2) = packed;
    }
    __syncthreads();

    { // per-pixel |x-y| for gen-loss L1 over owned 4 px
      const int c = tid & 31, rg = tid >> 5;
      #pragma unroll
      for (int o = 0; o < 4; ++o) {
        const int r = HALO + rg * 4 + o;
        const unsigned int u = *(const unsigned int*)(XY + r * XYSTR + (HALO + c) * 2);
        absacc += fabsf(bf2f_lo(u) - bf2f_hi(u));
      }
    }

    if (ch == 0) {
      ssim_pass<4, 3, false>(0.5f, XY, P, tid, PIcs);
      ssim_pass<7, 2, false>(1.0f, XY, P, tid, PIcs);
      l1_pass<16>(8.0f, XY, P, tid, gl1);
    } else if (ch == 1) {
      ssim_pass<7, 1, false>(1.0f, XY, P, tid, PIcs);
      ssim_pass<13, 3, false>(2.0f, XY, P, tid, PIcs);
      ssim_pass<16, 1, false>(4.0f, XY, P, tid, PIcs);
      l1_pass<16>(8.0f, XY, P, tid, gl1);
    } else {
      ssim_pass<16, 2, false>(4.0f, XY, P, tid, PIcs);
      ssim_pass<16, 3, true>(8.0f, XY, P, tid, PIcs);
      l1_pass<16>(8.0f, XY, P, tid, gl1);
    }
  }

  float mixsum = 0.f;
  #pragma unroll
  for (int o = 0; o < 4; ++o) {
    const float ssim = 1.f - PIcs[o];
    mixsum += 200.f * (0.025f * ssim + 0.975f * (gl1[o] * (1.f / 3.f)));
  }

  // block reduction (4 waves)
  #pragma unroll
  for (int off = 32; off > 0; off >>= 1) {
    mixsum += __shfl_down(mixsum, off);
    absacc += __shfl_down(absacc, off);
  }
  const int wave = tid >> 6, lane = tid & 63;
  if (lane == 0) { red[wave] = mixsum; red[4 + wave] = absacc; }
  __syncthreads();
  if (tid == 0) {
    float m = 0.f, a = 0.f;
    #pragma unroll
    for (int i = 0; i < 4; ++i) { m += red[i]; a += red[4 + i]; }
    const int blk = (b * 16 + by) * 16 + bx;
    partials[2 * blk + 0] = m;
    partials[2 * blk + 1] = a;
  }
}

__global__ __launch_bounds__(512)
void msssim_final_kernel(const float* __restrict__ partials,
                         const float* __restrict__ disc,
                         float* __restrict__ out) {
  __shared__ float red[24];
  const int tid = threadIdx.x;
  float m = 0.f, a = 0.f, d2 = 0.f;
  for (int j = tid; j < 2048; j += 512) {
    m += partials[2 * j + 0];
    a += partials[2 * j + 1];
  }
  for (int i = tid; i < 8 * 62 * 62; i += 512) {
    const float d = disc[i] - 1.f;
    d2 = fmaf(d, d, d2);
  }
  #pragma unroll
  for (int off = 32; off > 0; off >>= 1) {
    m  += __shfl_down(m, off);
    a  += __shfl_down(a, off);
    d2 += __shfl_down(d2, off);
  }
  const int wave = tid >> 6, lane = tid & 63;
  if (lane == 0) { red[wave] = m; red[8 + wave] = a; red[16 + wave] = d2; }
  __syncthreads();
  if (tid == 0) {
    float sm = 0.f, sa = 0.f, sd = 0.f;
    #pragma unroll
    for (int i = 0; i < 8; ++i) { sm += red[i]; sa += red[8 + i]; sd += red[16 + i]; }
    const float mix_mean  = sm / (8.f * 512.f * 512.f);
    const float abs_mean  = sa / (8.f * 3.f * 512.f * 512.f);
    const float disc_mean = sd / (8.f * 62.f * 62.f);
    out[0] = 0.5f * (mix_mean + 100.f * abs_mean + disc_mean);
  }
}

extern "C" void kernel_launch(void* const* d_in, const int* in_sizes, int n_in,
                              void* d_out, int out_size, void* d_ws, size_t ws_size,
                              hipStream_t stream) {
  const float* x    = (const float*)d_in[0];
  const float* y    = (const float*)d_in[1];
  const float* disc = (const float*)d_in[2];
  // d_in[3] = g_masks (unused: weights recomputed on device)
  float* partials = (float*)d_ws;   // 2048*2 floats, fully overwritten each call
  dim3 grid(16, 16, 8);
  msssim_fused_kernel<<<grid, NT, 0, stream>>>(x, y, partials);
  msssim_final_kernel<<<1, 512, 0, stream>>>(partials, disc, (float*)d_out);
}

// Round 6
// 222.050 us; speedup vs baseline: 2.9257x; 2.5549x over previous
//
#include <hip/hip_runtime.h>
#include <stdint.h>

// MS-SSIM + L1 fused loss, MI355X.
// R6: MFMA rewrite. Both separable-conv passes become banded GEMMs on the
// bf16 matrix cores (K=64 uniform, zero-padded taps; one 32x64 weight
// matrix WM[m][k]=wfull[k-m] serves as B^T for H-pass and A for V-pass).
// 32x32 tile/block, 256 thr (4 waves), halo 16, staging bf16 in LDS.
// H: D(64x32)=Xq(64x64)xWh ; P stored transposed bf16 (PT[n][k]) so the
// V-pass B-operand load is contiguous b128. V: D(32x32)=WM(32x64)xP.
// LDS ~74KB -> 2 blocks/CU. R5 was LDS/VALU bound at 530us; MFMA moves
// ~95% of the FLOPs to the matrix pipe.

#define TILE 32
#define HALO 16
#define WDIM 64            // staging dim = TILE + 2*HALO
#define SSTR 72            // bf16 stride (72*2=144B, 16B-multiple, conflict-min)
#define PLN  (64 * SSTR)   // XQ plane size (ush)
#define PTPLN (32 * SSTR)  // PT plane size (ush)
#define NT   256

#define C1c 1.0e-4f
#define C2c 9.0e-4f

typedef short bf16x8 __attribute__((ext_vector_type(8)));
typedef float f32x4  __attribute__((ext_vector_type(4)));

__device__ __forceinline__ float bf2f_lo(unsigned int u) {
  union { unsigned int u; float f; } c; c.u = u << 16; return c.f;
}
__device__ __forceinline__ float bf2f_hi(unsigned int u) {
  union { unsigned int u; float f; } c; c.u = u & 0xFFFF0000u; return c.f;
}
__device__ __forceinline__ unsigned short f2bf(float f) {
  union { float f; unsigned int u; } c; c.f = f;
  unsigned int r = (c.u + 0x7FFFu + ((c.u >> 16) & 1u)) >> 16;
  return (unsigned short)r;
}
__device__ __forceinline__ void st4bf(unsigned short* p, const float* v) {
  uint2 u;
  u.x = (unsigned int)f2bf(v[0]) | ((unsigned int)f2bf(v[1]) << 16);
  u.y = (unsigned int)f2bf(v[2]) | ((unsigned int)f2bf(v[3]) << 16);
  *(uint2*)p = u;
}

// Build WM[m][k] = wfull[k-m] (k-m in [0,32], else 0), wfull = normalized
// 33-tap gaussian. Leading sync protects prior readers of WM/wf/PT.
__device__ __forceinline__ void build_wm(float sigma, unsigned short* WM,
                                         float* wf, int tid) {
  __syncthreads();
  if (tid < 33) {
    const float d = (float)(tid - 16);
    wf[tid] = expf(-d * d / (2.0f * sigma * sigma));
  }
  __syncthreads();
  if (tid == 0) {
    float s = 0.f;
    for (int i = 0; i < 33; ++i) s += wf[i];
    wf[33] = 1.0f / s;
  }
  __syncthreads();
  const float si = wf[33];
  #pragma unroll
  for (int i = 0; i < 8; ++i) {
    const int idx = i * 256 + tid;      // 0..2047
    const int m = idx >> 6, k = idx & 63;
    const int t = k - m;
    const float v = (t >= 0 && t <= 32) ? wf[t] * si : 0.f;
    WM[m * SSTR + k] = f2bf(v);
  }
  __syncthreads();
}

// H-GEMM: per wave mt=wave. D(16x32 per wave x NQ) -> PT (transposed bf16).
template<int NQ>
__device__ __forceinline__ void hgemm(const unsigned short* __restrict__ XQ,
                                      int srcq0,
                                      const unsigned short* __restrict__ WM,
                                      unsigned short* __restrict__ PT,
                                      int wave, int lane) {
  const int l16 = lane & 15, quad = lane >> 4;
  const int m0 = wave * 16;
  #pragma unroll
  for (int q = 0; q < NQ; ++q) {
    const unsigned short* xp = XQ + (srcq0 + q) * PLN + (m0 + l16) * SSTR + quad * 8;
    const bf16x8 a0 = *(const bf16x8*)(xp);
    const bf16x8 a1 = *(const bf16x8*)(xp + 32);
    #pragma unroll
    for (int nt = 0; nt < 2; ++nt) {
      const unsigned short* wp = WM + (nt * 16 + l16) * SSTR + quad * 8;
      const bf16x8 b0 = *(const bf16x8*)(wp);
      const bf16x8 b1 = *(const bf16x8*)(wp + 32);
      f32x4 acc = {0.f, 0.f, 0.f, 0.f};
      acc = __builtin_amdgcn_mfma_f32_16x16x32_bf16(a0, b0, acc, 0, 0, 0);
      acc = __builtin_amdgcn_mfma_f32_16x16x32_bf16(a1, b1, acc, 0, 0, 0);
      // C layout: val(row=quad*4+r, col=l16); PT[n][k]: k=m0+quad*4+r contiguous
      uint2 u;
      u.x = (unsigned int)f2bf(acc[0]) | ((unsigned int)f2bf(acc[1]) << 16);
      u.y = (unsigned int)f2bf(acc[2]) | ((unsigned int)f2bf(acc[3]) << 16);
      *(uint2*)(PT + q * PTPLN + (nt * 16 + l16) * SSTR + m0 + quad * 4) = u;
    }
  }
}

// V-GEMM: wave handles output quadrant (mt=wave>>1, nt=wave&1), all NQ.
template<int NQ>
__device__ __forceinline__ void vgemm(const unsigned short* __restrict__ WM,
                                      const unsigned short* __restrict__ PT,
                                      int wave, int lane, f32x4* out) {
  const int l16 = lane & 15, quad = lane >> 4;
  const int m0 = (wave >> 1) * 16;
  const int n0 = (wave & 1) * 16;
  const unsigned short* ap = WM + (m0 + l16) * SSTR + quad * 8;
  const bf16x8 a0 = *(const bf16x8*)(ap);
  const bf16x8 a1 = *(const bf16x8*)(ap + 32);
  #pragma unroll
  for (int q = 0; q < NQ; ++q) {
    const unsigned short* pp = PT + q * PTPLN + (n0 + l16) * SSTR + quad * 8;
    const bf16x8 b0 = *(const bf16x8*)(pp);
    const bf16x8 b1 = *(const bf16x8*)(pp + 32);
    f32x4 acc = {0.f, 0.f, 0.f, 0.f};
    acc = __builtin_amdgcn_mfma_f32_16x16x32_bf16(a0, b0, acc, 0, 0, 0);
    acc = __builtin_amdgcn_mfma_f32_16x16x32_bf16(a1, b1, acc, 0, 0, 0);
    out[q] = acc;
  }
}

__global__ __launch_bounds__(NT)
void msssim_fused_kernel(const float* __restrict__ x, const float* __restrict__ y,
                         float* __restrict__ partials) {
  __shared__ unsigned short XQ[5 * PLN];     // planes: x, y, x2, y2, xy (bf16)
  __shared__ unsigned short PT[5 * PTPLN];   // H result, transposed, bf16
  __shared__ unsigned short WM[32 * SSTR];   // banded weight matrix, bf16
  __shared__ float wf[34];
  __shared__ float red[8];

  const int tid = threadIdx.x;
  const int wave = tid >> 6, lane = tid & 63;
  const int bx = blockIdx.x, by = blockIdx.y, b = blockIdx.z;
  const int x0 = bx * TILE - HALO;
  const int y0 = by * TILE - HALO;

  float PIcs[4] = {1.f, 1.f, 1.f, 1.f};
  float gl1[4]  = {0.f, 0.f, 0.f, 0.f};
  float absacc  = 0.f;

  for (int ch = 0; ch < 3; ++ch) {
    const float* __restrict__ xs = x + (size_t)(b * 3 + ch) * 512 * 512;
    const float* __restrict__ ys = y + (size_t)(b * 3 + ch) * 512 * 512;

    __syncthreads();   // previous channel readers of XQ done
    #pragma unroll
    for (int it = 0; it < 4; ++it) {
      const int r  = it * 16 + (tid >> 4);
      const int c4 = (tid & 15) * 4;
      const int gy = y0 + r;
      const int gx = x0 + c4;
      const bool rowok = (gy >= 0) && (gy < 512);
      float xv[4], yv[4];
      if (rowok && gx >= 0 && gx <= 508) {
        const float4 xf = *(const float4*)(xs + gy * 512 + gx);
        const float4 yf = *(const float4*)(ys + gy * 512 + gx);
        xv[0] = xf.x; xv[1] = xf.y; xv[2] = xf.z; xv[3] = xf.w;
        yv[0] = yf.x; yv[1] = yf.y; yv[2] = yf.z; yv[3] = yf.w;
      } else {
        #pragma unroll
        for (int e = 0; e < 4; ++e) {
          const int g = gx + e;
          const bool ok = rowok && (g >= 0) && (g < 512);
          xv[e] = ok ? xs[gy * 512 + g] : 0.f;
          yv[e] = ok ? ys[gy * 512 + g] : 0.f;
        }
      }
      float q2[4], q3[4], q4[4];
      #pragma unroll
      for (int e = 0; e < 4; ++e) {
        xv[e] = fmaf(xv[e], 0.5f, 0.5f);
        yv[e] = fmaf(yv[e], 0.5f, 0.5f);
        q2[e] = xv[e] * xv[e];
        q3[e] = yv[e] * yv[e];
        q4[e] = xv[e] * yv[e];
      }
      if (r >= 16 && r < 48 && c4 >= 16 && c4 < 48) {
        #pragma unroll
        for (int e = 0; e < 4; ++e) absacc += fabsf(xv[e] - yv[e]);
      }
      const int off = r * SSTR + c4;
      st4bf(XQ + 0 * PLN + off, xv);
      st4bf(XQ + 1 * PLN + off, yv);
      st4bf(XQ + 2 * PLN + off, q2);
      st4bf(XQ + 3 * PLN + off, q3);
      st4bf(XQ + 4 * PLN + off, q4);
    }
    __syncthreads();   // XQ complete

    // ---- SSIM sigma passes for this channel ----
    const int nsig = (ch == 1) ? 3 : 2;
    #pragma unroll 1
    for (int sidx = 0; sidx < nsig; ++sidx) {
      float sigma; int mult; bool last = false;
      if (ch == 0)      { sigma = sidx ? 1.0f : 0.5f; mult = sidx ? 2 : 3; }
      else if (ch == 1) { sigma = (sidx == 0) ? 1.0f : (sidx == 1 ? 2.0f : 4.0f);
                          mult  = (sidx == 1) ? 3 : 1; }
      else              { sigma = sidx ? 8.0f : 4.0f; mult = sidx ? 3 : 2;
                          last  = (sidx == 1); }
      build_wm(sigma, WM, wf, tid);             // leading sync inside
      hgemm<5>(XQ, 0, WM, PT, wave, lane);
      __syncthreads();
      f32x4 V[5];
      vgemm<5>(WM, PT, wave, lane, V);
      #pragma unroll
      for (int r = 0; r < 4; ++r) {
        const float mux = V[0][r], muy = V[1][r];
        const float A = mux * muy;
        const float B = mux * mux + muy * muy;
        const float S = V[2][r] + V[3][r] - B;
        const float sxy = V[4][r] - A;
        const float cs = (2.f * sxy + C2c) / (S + C2c);
        float p = cs;
        if (mult >= 2) p *= cs;
        if (mult >= 3) p *= cs;
        if (last) {
          const float l = (2.f * A + C1c) / (B + C1c);
          p *= l * l * l;
        }
        PIcs[r] *= p;
      }
    }

    // ---- gaussian L1 (sigma=8) ----
    build_wm(8.0f, WM, wf, tid);                // leading sync protects PT/WM
    // overwrite plane 4 with |x-y| (reads planes 0,1; disjoint writes)
    #pragma unroll
    for (int i = 0; i < 4; ++i) {
      const int idx = i * 256 + tid;            // 0..1023
      const int r = idx >> 4, c4 = (idx & 15) * 4;
      const int off = r * SSTR + c4;
      const uint2 ux = *(const uint2*)(XQ + 0 * PLN + off);
      const uint2 uy = *(const uint2*)(XQ + 1 * PLN + off);
      float d[4];
      d[0] = fabsf(bf2f_lo(ux.x) - bf2f_lo(uy.x));
      d[1] = fabsf(bf2f_hi(ux.x) - bf2f_hi(uy.x));
      d[2] = fabsf(bf2f_lo(ux.y) - bf2f_lo(uy.y));
      d[3] = fabsf(bf2f_hi(ux.y) - bf2f_hi(uy.y));
      st4bf(XQ + 4 * PLN + off, d);
    }
    __syncthreads();
    hgemm<1>(XQ, 4, WM, PT, wave, lane);
    __syncthreads();
    f32x4 V1[1];
    vgemm<1>(WM, PT, wave, lane, V1);
    #pragma unroll
    for (int r = 0; r < 4; ++r) gl1[r] += V1[0][r];
  }

  float mixsum = 0.f;
  #pragma unroll
  for (int r = 0; r < 4; ++r) {
    const float ssim = 1.f - PIcs[r];
    mixsum += 200.f * (0.025f * ssim + 0.975f * (gl1[r] * (1.f / 3.f)));
  }

  #pragma unroll
  for (int off = 32; off > 0; off >>= 1) {
    mixsum += __shfl_down(mixsum, off);
    absacc += __shfl_down(absacc, off);
  }
  if (lane == 0) { red[wave] = mixsum; red[4 + wave] = absacc; }
  __syncthreads();
  if (tid == 0) {
    float m = 0.f, a = 0.f;
    #pragma unroll
    for (int i = 0; i < 4; ++i) { m += red[i]; a += red[4 + i]; }
    const int blk = (b * 16 + by) * 16 + bx;
    partials[2 * blk + 0] = m;
    partials[2 * blk + 1] = a;
  }
}

__global__ __launch_bounds__(512)
void msssim_final_kernel(const float* __restrict__ partials,
                         const float* __restrict__ disc,
                         float* __restrict__ out) {
  __shared__ float red[24];
  const int tid = threadIdx.x;
  float m = 0.f, a = 0.f, d2 = 0.f;
  for (int j = tid; j < 2048; j += 512) {
    m += partials[2 * j + 0];
    a += partials[2 * j + 1];
  }
  for (int i = tid; i < 8 * 62 * 62; i += 512) {
    const float d = disc[i] - 1.f;
    d2 = fmaf(d, d, d2);
  }
  #pragma unroll
  for (int off = 32; off > 0; off >>= 1) {
    m  += __shfl_down(m, off);
    a  += __shfl_down(a, off);
    d2 += __shfl_down(d2, off);
  }
  const int wave = tid >> 6, lane = tid & 63;
  if (lane == 0) { red[wave] = m; red[8 + wave] = a; red[16 + wave] = d2; }
  __syncthreads();
  if (tid == 0) {
    float sm = 0.f, sa = 0.f, sd = 0.f;
    #pragma unroll
    for (int i = 0; i < 8; ++i) { sm += red[i]; sa += red[8 + i]; sd += red[16 + i]; }
    const float mix_mean  = sm / (8.f * 512.f * 512.f);
    const float abs_mean  = sa / (8.f * 3.f * 512.f * 512.f);
    const float disc_mean = sd / (8.f * 62.f * 62.f);
    out[0] = 0.5f * (mix_mean + 100.f * abs_mean + disc_mean);
  }
}

extern "C" void kernel_launch(void* const* d_in, const int* in_sizes, int n_in,
                              void* d_out, int out_size, void* d_ws, size_t ws_size,
                              hipStream_t stream) {
  const float* x    = (const float*)d_in[0];
  const float* y    = (const float*)d_in[1];
  const float* disc = (const float*)d_in[2];
  // d_in[3] = g_masks (unused: weights recomputed on device)
  float* partials = (float*)d_ws;   // 2048*2 floats, fully overwritten each call
  dim3 grid(16, 16, 8);
  msssim_fused_kernel<<<grid, NT, 0, stream>>>(x, y, partials);
  msssim_final_kernel<<<1, 512, 0, stream>>>(partials, disc, (float*)d_out);
}